// Round 1
// baseline (370.900 us; speedup 1.0000x reference)
//
#include <hip/hip_runtime.h>
#include <math.h>

// Tsit5 tableau
#define A21f 0.161f
#define A31f -0.008480655492356989f
#define A32f 0.335480655492357f
#define A41f 2.8971530571054935f
#define A42f -6.359448489975075f
#define A43f 4.3622954328695815f
#define A51f 5.325864828439257f
#define A52f -11.748883564062828f
#define A53f 7.4955393428898365f
#define A54f -0.09249506636175525f
#define A61f 5.86145544294642f
#define A62f -12.92096931784711f
#define A63f 8.159367898576159f
#define A64f -0.071584973281401f
#define A65f -0.028269050394068383f
#define B1f 0.09646076681806523f
#define B2f 0.01f
#define B3f 0.4798896504144996f
#define B4f 1.379008574103742f
#define B5f -3.290069515436081f
#define B6f 2.324710524099774f
#define E1f -0.00178001105222577714f
#define E2f -0.0008164344596567469f
#define E3f 0.007880878010261995f
#define E4f -0.1447110071732629f
#define E5f 0.5823571654525552f
#define E6f -0.45808210592918697f
#define E7f 0.015151515151515152f

#define WPB 4  // waves per block

__device__ __forceinline__ void wave_sync() {
    // scheduling barrier: keep LDS write->read program order within the wave
    __builtin_amdgcn_wave_barrier();
}

// JAX softplus(x) = logaddexp(x, 0) = max(x,0) + log1p(exp(-|x|))
__device__ __forceinline__ float sp(float x) {
    return fmaxf(x, 0.0f) + log1pf(expf(-fabsf(x)));
}

__global__ __launch_bounds__(256, 4)
void ode_kernel(const float* __restrict__ x0s,
                const float* __restrict__ W1, const float* __restrict__ b1,
                const float* __restrict__ W2, const float* __restrict__ b2,
                const float* __restrict__ W3, const float* __restrict__ b3,
                const void* __restrict__ Tptr,
                float* __restrict__ out, int out_size, int B)
{
    __shared__ __align__(16) float lds_u[WPB][64];
    __shared__ __align__(16) float lds_h[WPB][32];

    const int wave = threadIdx.x >> 6;
    const int lane = threadIdx.x & 63;
    const int traj = blockIdx.x * WPB + wave;
    if (traj >= B) return;
    const int row  = lane & 31;
    const int half = lane >> 5;

    // ---- weights into per-lane registers ----
    float W1r[32], W2r[16], W3r[32];
#pragma unroll
    for (int j = 0; j < 32; ++j) W1r[j] = W1[row * 64 + half * 32 + j];
#pragma unroll
    for (int j = 0; j < 16; ++j) W2r[j] = W2[row * 32 + half * 16 + j];
#pragma unroll
    for (int j = 0; j < 32; ++j) W3r[j] = W3[lane * 32 + j];
    const float b1r = b1[row], b2r = b2[row], b3r = b3[lane];

    float* uB = lds_u[wave];
    float* hB = lds_h[wave];

    // f(u): MLP eval; u distributed lane-wise, returns lane-wise output
    auto f = [&](float u) -> float {
        wave_sync();
        uB[lane] = u;
        wave_sync();
        float a0 = 0.f, a1 = 0.f, a2 = 0.f, a3 = 0.f;
        const float4* up4 = (const float4*)(uB + (half << 5));
#pragma unroll
        for (int j = 0; j < 8; ++j) {
            float4 v = up4[j];
            a0 = fmaf(W1r[4 * j + 0], v.x, a0);
            a1 = fmaf(W1r[4 * j + 1], v.y, a1);
            a2 = fmaf(W1r[4 * j + 2], v.z, a2);
            a3 = fmaf(W1r[4 * j + 3], v.w, a3);
        }
        float acc = (a0 + a1) + (a2 + a3);
        acc += __shfl_xor(acc, 32);
        float h1 = sp(acc + b1r);
        wave_sync();
        if (lane < 32) hB[lane] = h1;
        wave_sync();
        a0 = a1 = a2 = a3 = 0.f;
        const float4* hp4 = (const float4*)(hB + (half << 4));
#pragma unroll
        for (int j = 0; j < 4; ++j) {
            float4 v = hp4[j];
            a0 = fmaf(W2r[4 * j + 0], v.x, a0);
            a1 = fmaf(W2r[4 * j + 1], v.y, a1);
            a2 = fmaf(W2r[4 * j + 2], v.z, a2);
            a3 = fmaf(W2r[4 * j + 3], v.w, a3);
        }
        acc = (a0 + a1) + (a2 + a3);
        acc += __shfl_xor(acc, 32);
        float h2 = sp(acc + b2r);
        wave_sync();
        if (lane < 32) hB[lane] = h2;
        wave_sync();
        a0 = a1 = a2 = a3 = 0.f;
        const float4* gp4 = (const float4*)hB;
#pragma unroll
        for (int j = 0; j < 8; ++j) {
            float4 v = gp4[j];
            a0 = fmaf(W3r[4 * j + 0], v.x, a0);
            a1 = fmaf(W3r[4 * j + 1], v.y, a1);
            a2 = fmaf(W3r[4 * j + 2], v.z, a2);
            a3 = fmaf(W3r[4 * j + 3], v.w, a3);
        }
        return ((a0 + a1) + (a2 + a3)) + b3r;
    };

    // T may arrive as int32/int64 (python scalar) — read first 4B as int, sanity-check
    int ti = *(const int*)Tptr;
    float Tf = (ti > 0 && ti < 1000000) ? (float)ti : *(const float*)Tptr;
    const float ts_step = Tf / 10.0f;

    float y = x0s[traj * 64 + lane];
    out[traj * 704 + lane] = y;   // ts[0] snapshot

    float t = 0.0f;
    float dt = 1e-3f;
    int n = 0;

    float k1 = f(y);  // FSAL seed (bitwise == reference's recompute of f(y))

    for (int iv = 1; iv <= 10; ++iv) {
        const float t_target = (iv == 10) ? Tf : ts_step * (float)iv;
        for (int it = 0; it < 64; ++it) {
            const float remaining = t_target - t;
            if (remaining <= 1e-12f) break;   // == reference masked no-op
            const float h = fminf(dt, fmaxf(remaining, 0.0f));

            float k2 = f(y + h * (A21f * k1));
            float k3 = f(y + h * (A31f * k1 + A32f * k2));
            float k4 = f(y + h * (A41f * k1 + A42f * k2 + A43f * k3));
            float k5 = f(y + h * (A51f * k1 + A52f * k2 + A53f * k3 + A54f * k4));
            float k6 = f(y + h * (A61f * k1 + A62f * k2 + A63f * k3 + A64f * k4 + A65f * k5));
            float y5 = y + h * (B1f * k1 + B2f * k2 + B3f * k3 + B4f * k4 + B5f * k5 + B6f * k6);
            float k7 = f(y5);
            float err = h * (E1f * k1 + E2f * k2 + E3f * k3 + E4f * k4 + E5f * k5 + E6f * k6 + E7f * k7);

            float scale = 1e-6f + 1e-3f * fmaxf(fabsf(y), fabsf(y5));
            float r = err / scale;
            float s = r * r;
#pragma unroll
            for (int m = 32; m >= 1; m >>= 1) s += __shfl_xor(s, m);
            float enorm = fmaxf(sqrtf(s * (1.0f / 64.0f)), 1e-10f);

            bool accept = enorm <= 1.0f;
            float fac = 0.9f * expf(-0.2f * logf(enorm));   // 0.9 * enorm^-0.2
            fac = fminf(fmaxf(fac, 0.1f), 5.0f);

            if (accept) { t += h; y = y5; k1 = k7; }
            dt = fmaxf(h * fac, 1e-8f);
            ++n;
        }
        out[traj * 704 + iv * 64 + lane] = y;
    }

    if (lane == 0) atomicAdd(out + (out_size - 1), (float)n);
}

__global__ void init_n(float* p) { *p = 0.0f; }

extern "C" void kernel_launch(void* const* d_in, const int* in_sizes, int n_in,
                              void* d_out, int out_size, void* d_ws, size_t ws_size,
                              hipStream_t stream) {
    const float* x0s = (const float*)d_in[0];
    const float* W1  = (const float*)d_in[1];
    const float* b1  = (const float*)d_in[2];
    const float* W2  = (const float*)d_in[3];
    const float* b2  = (const float*)d_in[4];
    const float* W3  = (const float*)d_in[5];
    const float* b3  = (const float*)d_in[6];
    const void*  Tp  = d_in[7];
    float* out = (float*)d_out;

    const int B = in_sizes[0] / 64;
    const int grid = (B + WPB - 1) / WPB;

    init_n<<<1, 1, 0, stream>>>(out + (out_size - 1));
    ode_kernel<<<grid, 256, 0, stream>>>(x0s, W1, b1, W2, b2, W3, b3, Tp,
                                         out, out_size, B);
}

// Round 2
// 347.098 us; speedup vs baseline: 1.0686x; 1.0686x over previous
//
#include <hip/hip_runtime.h>
#include <math.h>

// Tsit5 tableau
#define A21f 0.161f
#define A31f -0.008480655492356989f
#define A32f 0.335480655492357f
#define A41f 2.8971530571054935f
#define A42f -6.359448489975075f
#define A43f 4.3622954328695815f
#define A51f 5.325864828439257f
#define A52f -11.748883564062828f
#define A53f 7.4955393428898365f
#define A54f -0.09249506636175525f
#define A61f 5.86145544294642f
#define A62f -12.92096931784711f
#define A63f 8.159367898576159f
#define A64f -0.071584973281401f
#define A65f -0.028269050394068383f
#define B1f 0.09646076681806523f
#define B2f 0.01f
#define B3f 0.4798896504144996f
#define B4f 1.379008574103742f
#define B5f -3.290069515436081f
#define B6f 2.324710524099774f
#define E1f -0.00178001105222577714f
#define E2f -0.0008164344596567469f
#define E3f 0.007880878010261995f
#define E4f -0.1447110071732629f
#define E5f 0.5823571654525552f
#define E6f -0.45808210592918697f
#define E7f 0.015151515151515152f

#define WPB 4  // waves per block

__device__ __forceinline__ void wave_sync() {
    __builtin_amdgcn_wave_barrier();
}

// softplus(x) = max(x,0) + log1p(exp(-|x|)), via hw exp2/log2:
//   = max(x,0) + ln2 * log2(1 + 2^(-|x|*log2e))
__device__ __forceinline__ float sp(float x) {
    float t = exp2f(-fabsf(x) * 1.44269504088896341f);
    return fmaxf(x, 0.0f) + 0.69314718055994531f * __log2f(1.0f + t);
}

__global__ __launch_bounds__(256)
__attribute__((amdgpu_waves_per_eu(4, 4)))
void ode_kernel(const float* __restrict__ x0s,
                const float* __restrict__ W1, const float* __restrict__ b1,
                const float* __restrict__ W2, const float* __restrict__ b2,
                const float* __restrict__ W3, const float* __restrict__ b3,
                const void* __restrict__ Tptr,
                float* __restrict__ out, int out_size, int B)
{
    __shared__ __align__(16) float lds_u[WPB][64];
    __shared__ __align__(16) float lds_h[WPB][32];

    const int wave = threadIdx.x >> 6;
    const int lane = threadIdx.x & 63;
    const int traj = blockIdx.x * WPB + wave;
    if (traj >= B) return;
    const int row  = lane & 31;
    const int half = lane >> 5;

    // ---- weights into per-lane registers (80 VGPRs; waves_per_eu(4,4) gives
    // a 128-VGPR budget so these must NOT spill) ----
    float W1r[32], W2r[16], W3r[32];
#pragma unroll
    for (int j = 0; j < 32; ++j) W1r[j] = W1[row * 64 + half * 32 + j];
#pragma unroll
    for (int j = 0; j < 16; ++j) W2r[j] = W2[row * 32 + half * 16 + j];
#pragma unroll
    for (int j = 0; j < 32; ++j) W3r[j] = W3[lane * 32 + j];
    const float b1r = b1[row], b2r = b2[row], b3r = b3[lane];

    float* uB = lds_u[wave];
    float* hB = lds_h[wave];

    auto f = [&](float u) -> float {
        wave_sync();
        uB[lane] = u;
        wave_sync();
        float a0 = 0.f, a1 = 0.f, a2 = 0.f, a3 = 0.f;
        const float4* up4 = (const float4*)(uB + (half << 5));
#pragma unroll
        for (int j = 0; j < 8; ++j) {
            float4 v = up4[j];
            a0 = fmaf(W1r[4 * j + 0], v.x, a0);
            a1 = fmaf(W1r[4 * j + 1], v.y, a1);
            a2 = fmaf(W1r[4 * j + 2], v.z, a2);
            a3 = fmaf(W1r[4 * j + 3], v.w, a3);
        }
        float acc = (a0 + a1) + (a2 + a3);
        acc += __shfl_xor(acc, 32);
        float h1 = sp(acc + b1r);
        wave_sync();
        if (lane < 32) hB[lane] = h1;
        wave_sync();
        a0 = a1 = a2 = a3 = 0.f;
        const float4* hp4 = (const float4*)(hB + (half << 4));
#pragma unroll
        for (int j = 0; j < 4; ++j) {
            float4 v = hp4[j];
            a0 = fmaf(W2r[4 * j + 0], v.x, a0);
            a1 = fmaf(W2r[4 * j + 1], v.y, a1);
            a2 = fmaf(W2r[4 * j + 2], v.z, a2);
            a3 = fmaf(W2r[4 * j + 3], v.w, a3);
        }
        acc = (a0 + a1) + (a2 + a3);
        acc += __shfl_xor(acc, 32);
        float h2 = sp(acc + b2r);
        wave_sync();
        if (lane < 32) hB[lane] = h2;
        wave_sync();
        a0 = a1 = a2 = a3 = 0.f;
        const float4* gp4 = (const float4*)hB;
#pragma unroll
        for (int j = 0; j < 8; ++j) {
            float4 v = gp4[j];
            a0 = fmaf(W3r[4 * j + 0], v.x, a0);
            a1 = fmaf(W3r[4 * j + 1], v.y, a1);
            a2 = fmaf(W3r[4 * j + 2], v.z, a2);
            a3 = fmaf(W3r[4 * j + 3], v.w, a3);
        }
        return ((a0 + a1) + (a2 + a3)) + b3r;
    };

    int ti = *(const int*)Tptr;
    float Tf = (ti > 0 && ti < 1000000) ? (float)ti : *(const float*)Tptr;
    const float ts_step = Tf / 10.0f;

    float y = x0s[traj * 64 + lane];
    out[traj * 704 + lane] = y;

    float t = 0.0f;
    float dt = 1e-3f;
    int n = 0;

    float k1 = f(y);  // FSAL seed

    for (int iv = 1; iv <= 10; ++iv) {
        const float t_target = (iv == 10) ? Tf : ts_step * (float)iv;
        for (int it = 0; it < 64; ++it) {
            const float remaining = t_target - t;
            if (remaining <= 1e-12f) break;
            const float h = fminf(dt, fmaxf(remaining, 0.0f));

            float k2 = f(y + h * (A21f * k1));
            float k3 = f(y + h * (A31f * k1 + A32f * k2));
            float k4 = f(y + h * (A41f * k1 + A42f * k2 + A43f * k3));
            float k5 = f(y + h * (A51f * k1 + A52f * k2 + A53f * k3 + A54f * k4));
            float k6 = f(y + h * (A61f * k1 + A62f * k2 + A63f * k3 + A64f * k4 + A65f * k5));
            float y5 = y + h * (B1f * k1 + B2f * k2 + B3f * k3 + B4f * k4 + B5f * k5 + B6f * k6);
            float k7 = f(y5);
            float err = h * (E1f * k1 + E2f * k2 + E3f * k3 + E4f * k4 + E5f * k5 + E6f * k6 + E7f * k7);

            float scale = 1e-6f + 1e-3f * fmaxf(fabsf(y), fabsf(y5));
            float r = err / scale;
            float s = r * r;
#pragma unroll
            for (int m = 32; m >= 1; m >>= 1) s += __shfl_xor(s, m);
            float enorm = fmaxf(sqrtf(s * (1.0f / 64.0f)), 1e-10f);

            bool accept = enorm <= 1.0f;
            float fac = 0.9f * exp2f(-0.2f * __log2f(enorm));  // 0.9 * enorm^-0.2
            fac = fminf(fmaxf(fac, 0.1f), 5.0f);

            if (accept) { t += h; y = y5; k1 = k7; }
            dt = fmaxf(h * fac, 1e-8f);
            ++n;
        }
        out[traj * 704 + iv * 64 + lane] = y;
    }

    if (lane == 0) atomicAdd(out + (out_size - 1), (float)n);
}

__global__ void init_n(float* p) { *p = 0.0f; }

extern "C" void kernel_launch(void* const* d_in, const int* in_sizes, int n_in,
                              void* d_out, int out_size, void* d_ws, size_t ws_size,
                              hipStream_t stream) {
    const float* x0s = (const float*)d_in[0];
    const float* W1  = (const float*)d_in[1];
    const float* b1  = (const float*)d_in[2];
    const float* W2  = (const float*)d_in[3];
    const float* b2  = (const float*)d_in[4];
    const float* W3  = (const float*)d_in[5];
    const float* b3  = (const float*)d_in[6];
    const void*  Tp  = d_in[7];
    float* out = (float*)d_out;

    const int B = in_sizes[0] / 64;
    const int grid = (B + WPB - 1) / WPB;

    init_n<<<1, 1, 0, stream>>>(out + (out_size - 1));
    ode_kernel<<<grid, 256, 0, stream>>>(x0s, W1, b1, W2, b2, W3, b3, Tp,
                                         out, out_size, B);
}

// Round 3
// 205.058 us; speedup vs baseline: 1.8088x; 1.6927x over previous
//
#include <hip/hip_runtime.h>
#include <math.h>

// Tsit5 tableau
#define A21f 0.161f
#define A31f -0.008480655492356989f
#define A32f 0.335480655492357f
#define A41f 2.8971530571054935f
#define A42f -6.359448489975075f
#define A43f 4.3622954328695815f
#define A51f 5.325864828439257f
#define A52f -11.748883564062828f
#define A53f 7.4955393428898365f
#define A54f -0.09249506636175525f
#define A61f 5.86145544294642f
#define A62f -12.92096931784711f
#define A63f 8.159367898576159f
#define A64f -0.071584973281401f
#define A65f -0.028269050394068383f
#define B1f 0.09646076681806523f
#define B2f 0.01f
#define B3f 0.4798896504144996f
#define B4f 1.379008574103742f
#define B5f -3.290069515436081f
#define B6f 2.324710524099774f
#define E1f -0.00178001105222577714f
#define E2f -0.0008164344596567469f
#define E3f 0.007880878010261995f
#define E4f -0.1447110071732629f
#define E5f 0.5823571654525552f
#define E6f -0.45808210592918697f
#define E7f 0.015151515151515152f

#define WPB 4  // waves per block

__device__ __forceinline__ void wave_sync() {
    __builtin_amdgcn_wave_barrier();
}

// softplus(x) = max(x,0) + ln2 * log2(1 + 2^(-|x|*log2e))  (hw exp2/log2)
__device__ __forceinline__ float sp(float x) {
    float t = exp2f(-fabsf(x) * 1.44269504088896341f);
    return fmaxf(x, 0.0f) + 0.69314718055994531f * __log2f(1.0f + t);
}

__global__ __launch_bounds__(256)
__attribute__((amdgpu_waves_per_eu(4, 4)))
void ode_kernel(const float* __restrict__ x0s,
                const float* __restrict__ W1, const float* __restrict__ b1,
                const float* __restrict__ W2, const float* __restrict__ b2,
                const float* __restrict__ W3, const float* __restrict__ b3,
                const void* __restrict__ Tptr,
                float* __restrict__ out, int out_size, int B)
{
    __shared__ __align__(16) float lds_u[WPB][64];
    __shared__ __align__(16) float lds_h[WPB][32];

    const int wave = threadIdx.x >> 6;
    const int lane = threadIdx.x & 63;
    const int traj = blockIdx.x * WPB + wave;
    if (traj >= B) return;
    const int row  = lane & 31;
    const int half = lane >> 5;

    // ---- weights into per-lane registers; inline-asm pins force VGPR
    // residency (compiler was spilling these to scratch: 79 MB WRITE_SIZE,
    // ~220 us of L2-bound reloads at VGPR_Count=64) ----
    float W1r[32], W2r[16], W3r[32];
#pragma unroll
    for (int j = 0; j < 32; ++j) W1r[j] = W1[row * 64 + half * 32 + j];
#pragma unroll
    for (int j = 0; j < 16; ++j) W2r[j] = W2[row * 32 + half * 16 + j];
#pragma unroll
    for (int j = 0; j < 32; ++j) W3r[j] = W3[lane * 32 + j];
#pragma unroll
    for (int j = 0; j < 32; ++j) asm("" : "+v"(W1r[j]));
#pragma unroll
    for (int j = 0; j < 16; ++j) asm("" : "+v"(W2r[j]));
#pragma unroll
    for (int j = 0; j < 32; ++j) asm("" : "+v"(W3r[j]));
    const float b1r = b1[row], b2r = b2[row], b3r = b3[lane];

    float* uB = lds_u[wave];
    float* hB = lds_h[wave];

    auto f = [&](float u) -> float {
        wave_sync();
        uB[lane] = u;
        wave_sync();
        float a0 = 0.f, a1 = 0.f, a2 = 0.f, a3 = 0.f;
        const float4* up4 = (const float4*)(uB + (half << 5));
#pragma unroll
        for (int j = 0; j < 8; ++j) {
            float4 v = up4[j];
            a0 = fmaf(W1r[4 * j + 0], v.x, a0);
            a1 = fmaf(W1r[4 * j + 1], v.y, a1);
            a2 = fmaf(W1r[4 * j + 2], v.z, a2);
            a3 = fmaf(W1r[4 * j + 3], v.w, a3);
        }
        float acc = (a0 + a1) + (a2 + a3);
        acc += __shfl_xor(acc, 32);
        float h1 = sp(acc + b1r);
        wave_sync();
        if (lane < 32) hB[lane] = h1;
        wave_sync();
        a0 = a1 = a2 = a3 = 0.f;
        const float4* hp4 = (const float4*)(hB + (half << 4));
#pragma unroll
        for (int j = 0; j < 4; ++j) {
            float4 v = hp4[j];
            a0 = fmaf(W2r[4 * j + 0], v.x, a0);
            a1 = fmaf(W2r[4 * j + 1], v.y, a1);
            a2 = fmaf(W2r[4 * j + 2], v.z, a2);
            a3 = fmaf(W2r[4 * j + 3], v.w, a3);
        }
        acc = (a0 + a1) + (a2 + a3);
        acc += __shfl_xor(acc, 32);
        float h2 = sp(acc + b2r);
        wave_sync();
        if (lane < 32) hB[lane] = h2;
        wave_sync();
        a0 = a1 = a2 = a3 = 0.f;
        const float4* gp4 = (const float4*)hB;
#pragma unroll
        for (int j = 0; j < 8; ++j) {
            float4 v = gp4[j];
            a0 = fmaf(W3r[4 * j + 0], v.x, a0);
            a1 = fmaf(W3r[4 * j + 1], v.y, a1);
            a2 = fmaf(W3r[4 * j + 2], v.z, a2);
            a3 = fmaf(W3r[4 * j + 3], v.w, a3);
        }
        return ((a0 + a1) + (a2 + a3)) + b3r;
    };

    int ti = *(const int*)Tptr;
    float Tf = (ti > 0 && ti < 1000000) ? (float)ti : *(const float*)Tptr;
    const float ts_step = Tf / 10.0f;

    float y = x0s[traj * 64 + lane];
    out[traj * 704 + lane] = y;

    float t = 0.0f;
    float dt = 1e-3f;
    int n = 0;

    float k1 = f(y);  // FSAL seed

    for (int iv = 1; iv <= 10; ++iv) {
        const float t_target = (iv == 10) ? Tf : ts_step * (float)iv;
        for (int it = 0; it < 64; ++it) {
            const float remaining = t_target - t;
            if (remaining <= 1e-12f) break;
            const float h = fminf(dt, fmaxf(remaining, 0.0f));

            float k2 = f(y + h * (A21f * k1));
            float k3 = f(y + h * (A31f * k1 + A32f * k2));
            float k4 = f(y + h * (A41f * k1 + A42f * k2 + A43f * k3));
            float k5 = f(y + h * (A51f * k1 + A52f * k2 + A53f * k3 + A54f * k4));
            float k6 = f(y + h * (A61f * k1 + A62f * k2 + A63f * k3 + A64f * k4 + A65f * k5));
            float y5 = y + h * (B1f * k1 + B2f * k2 + B3f * k3 + B4f * k4 + B5f * k5 + B6f * k6);
            float k7 = f(y5);
            float err = h * (E1f * k1 + E2f * k2 + E3f * k3 + E4f * k4 + E5f * k5 + E6f * k6 + E7f * k7);

            float scale = 1e-6f + 1e-3f * fmaxf(fabsf(y), fabsf(y5));
            float r = err / scale;
            float s = r * r;
#pragma unroll
            for (int m = 32; m >= 1; m >>= 1) s += __shfl_xor(s, m);
            float enorm = fmaxf(sqrtf(s * (1.0f / 64.0f)), 1e-10f);

            bool accept = enorm <= 1.0f;
            float fac = 0.9f * exp2f(-0.2f * __log2f(enorm));  // 0.9 * enorm^-0.2
            fac = fminf(fmaxf(fac, 0.1f), 5.0f);

            if (accept) { t += h; y = y5; k1 = k7; }
            dt = fmaxf(h * fac, 1e-8f);
            ++n;
        }
        out[traj * 704 + iv * 64 + lane] = y;
    }

    if (lane == 0) atomicAdd(out + (out_size - 1), (float)n);
}

__global__ void init_n(float* p) { *p = 0.0f; }

extern "C" void kernel_launch(void* const* d_in, const int* in_sizes, int n_in,
                              void* d_out, int out_size, void* d_ws, size_t ws_size,
                              hipStream_t stream) {
    const float* x0s = (const float*)d_in[0];
    const float* W1  = (const float*)d_in[1];
    const float* b1  = (const float*)d_in[2];
    const float* W2  = (const float*)d_in[3];
    const float* b2  = (const float*)d_in[4];
    const float* W3  = (const float*)d_in[5];
    const float* b3  = (const float*)d_in[6];
    const void*  Tp  = d_in[7];
    float* out = (float*)d_out;

    const int B = in_sizes[0] / 64;
    const int grid = (B + WPB - 1) / WPB;

    init_n<<<1, 1, 0, stream>>>(out + (out_size - 1));
    ode_kernel<<<grid, 256, 0, stream>>>(x0s, W1, b1, W2, b2, W3, b3, Tp,
                                         out, out_size, B);
}